// Round 13
// baseline (715.778 us; speedup 1.0000x reference)
//
#include <hip/hip_runtime.h>

// LightGCL forward: 2 layers of bipartite SpMM + mean of layer embeddings.
// Deterministic bucket build (no global atomics): per-block LDS histograms ->
// cnts16, per-bucket scan -> exact chunk offsets, atomic-free emit. Fused
// sort-by-row + layer-1 accumulate per 64-row bucket (LDS staging, 4 gather
// slots); layer-2 accumulate streams sorted entries with accum6-style 4-slot
// 2-deep pipeline at full occupancy (256 thr, launch_bounds(256,8)).
// No atomics and no LDS in any gather hot loop.

constexpr int D = 64;
constexpr int RPB = 64;             // rows per sort bucket
constexpr int ACC = 32;             // rows per accum-L2 block
constexpr int NBMAX = 5120;         // LDS histogram capacity
constexpr int REF_CAP = 4000;       // sort LDS staging capacity (entries)
constexpr int PASSB_EDGES = 8192;   // edges per block in count/emit

static __device__ __forceinline__ unsigned short f32_to_bf16(float f) {
    unsigned u = __float_as_uint(f);
    unsigned r = u + 0x7FFFu + ((u >> 16) & 1u);
    return (unsigned short)(r >> 16);
}
static __device__ __forceinline__ float bf16_lo(unsigned g) {
    return __uint_as_float(g << 16);
}
static __device__ __forceinline__ float bf16_hi(unsigned g) {
    return __uint_as_float(g & 0xFFFF0000u);
}

// ---------------- deterministic bucket build (no global atomics) ----------

__global__ __launch_bounds__(1024) void count_kernel(
    const int* __restrict__ rows, const int* __restrict__ cols,
    unsigned short* __restrict__ cnts16, int nu, int nnz, int NB) {
    __shared__ int cnt[NBMAX];
    for (int i = threadIdx.x; i < NB; i += 1024) cnt[i] = 0;
    __syncthreads();
    int base = blockIdx.x * PASSB_EDGES;
    for (int k = 0; k < PASSB_EDGES / 1024; k++) {
        int e = base + k * 1024 + threadIdx.x;
        if (e < nnz) {
            atomicAdd(&cnt[rows[e] >> 6], 1);
            atomicAdd(&cnt[(nu + cols[e]) >> 6], 1);
        }
    }
    __syncthreads();
    for (int i = threadIdx.x; i < NB; i += 1024)
        cnts16[(size_t)blockIdx.x * NB + i] = (unsigned short)cnt[i];
}

__global__ __launch_bounds__(64) void scanA_kernel(
    const unsigned short* __restrict__ cnts16, int* __restrict__ offs,
    int* __restrict__ totals, int NB, int NBLK) {
    int b = blockIdx.x;
    int lane = threadIdx.x;
    int carry = 0;
    for (int c0 = 0; c0 < NBLK; c0 += 64) {
        int blk = c0 + lane;
        int v = (blk < NBLK) ? (int)cnts16[(size_t)blk * NB + b] : 0;
        int x = v;
        for (int off = 1; off < 64; off <<= 1) {
            int n = __shfl_up(x, off, 64);
            if (lane >= off) x += n;
        }
        if (blk < NBLK) offs[(size_t)b * NBLK + blk] = carry + x - v;
        carry += __shfl(x, 63, 64);
    }
    if (lane == 0) totals[b] = carry;
}

__global__ void scan_buckets(const int* __restrict__ bktCnt,
                             int* __restrict__ bktBase, int* __restrict__ bktCur,
                             int NB, int total) {
    __shared__ int tsum[256];
    int t = threadIdx.x;
    const int IT = (NB + 255) / 256;  // <= 20
    int v[20];
    int s = 0;
    for (int k = 0; k < IT; k++) {
        int i = t * IT + k;
        v[k] = (i < NB) ? bktCnt[i] : 0;
        s += v[k];
    }
    tsum[t] = s;
    __syncthreads();
    for (int off = 1; off < 256; off <<= 1) {
        int x = (t >= off) ? tsum[t - off] : 0;
        __syncthreads();
        tsum[t] += x;
        __syncthreads();
    }
    int excl = (t > 0) ? tsum[t - 1] : 0;
    for (int k = 0; k < IT; k++) {
        int i = t * IT + k;
        if (i < NB) { bktBase[i] = excl; bktCur[i] = excl; excl += v[k]; }
    }
    if (t == 255) bktBase[NB] = total;
}

__global__ __launch_bounds__(1024) void passB_kernel(
    const float* __restrict__ vals, const int* __restrict__ rows,
    const int* __restrict__ cols, const int* __restrict__ bktBase,
    const int* __restrict__ offs, int2* __restrict__ tmp,
    int nu, int nnz, int NB, int NBLK) {
    __shared__ int cur[NBMAX];
    for (int i = threadIdx.x; i < NB; i += 1024)
        cur[i] = bktBase[i] + offs[(size_t)i * NBLK + blockIdx.x];
    __syncthreads();
    int base = blockIdx.x * PASSB_EDGES;
    for (int k = 0; k < PASSB_EDGES / 1024; k++) {
        int e = base + k * 1024 + threadIdx.x;
        if (e < nnz) {
            int r = rows[e], c = cols[e];
            int iv = __float_as_int(vals[e]);
            int gi = nu + c;
            int p1 = atomicAdd(&cur[r >> 6], 1);
            tmp[p1] = make_int2(((r & 63) << 19) | gi, iv);
            int p2 = atomicAdd(&cur[gi >> 6], 1);
            tmp[p2] = make_int2(((gi & 63) << 19) | r, iv);
        }
    }
}

// ---------------- mid-tier bucket build (global-atomic chunk reservation) --

__global__ __launch_bounds__(1024) void bucket_hist(
    const int* __restrict__ rows, const int* __restrict__ cols,
    int* __restrict__ bktCnt, int nu, int nnz, int NB) {
    __shared__ int cnt[NBMAX];
    for (int i = threadIdx.x; i < NB; i += blockDim.x) cnt[i] = 0;
    __syncthreads();
    int stride = gridDim.x * blockDim.x;
    for (int e = blockIdx.x * blockDim.x + threadIdx.x; e < nnz; e += stride) {
        atomicAdd(&cnt[rows[e] >> 6], 1);
        atomicAdd(&cnt[(nu + cols[e]) >> 6], 1);
    }
    __syncthreads();
    for (int i = threadIdx.x; i < NB; i += blockDim.x)
        if (cnt[i]) atomicAdd(&bktCnt[i], cnt[i]);
}

__global__ __launch_bounds__(1024) void pass_bucket(
    const float* __restrict__ vals, const int* __restrict__ rows,
    const int* __restrict__ cols, int* __restrict__ bktCur,
    int2* __restrict__ tmp, int nu, int nnz, int NB) {
    __shared__ int cnt[NBMAX];
    for (int i = threadIdx.x; i < NB; i += 1024) cnt[i] = 0;
    __syncthreads();
    int base = blockIdx.x * PASSB_EDGES;
    for (int k = 0; k < PASSB_EDGES / 1024; k++) {
        int e = base + k * 1024 + threadIdx.x;
        if (e < nnz) {
            atomicAdd(&cnt[rows[e] >> 6], 1);
            atomicAdd(&cnt[(nu + cols[e]) >> 6], 1);
        }
    }
    __syncthreads();
    for (int i = threadIdx.x; i < NB; i += 1024) {
        int c = cnt[i];
        if (c) cnt[i] = atomicAdd(&bktCur[i], c);
    }
    __syncthreads();
    for (int k = 0; k < PASSB_EDGES / 1024; k++) {
        int e = base + k * 1024 + threadIdx.x;
        if (e < nnz) {
            int r = rows[e], c = cols[e];
            int iv = __float_as_int(vals[e]);
            int gi = nu + c;
            int p1 = atomicAdd(&cnt[r >> 6], 1);
            tmp[p1] = make_int2(((r & 63) << 19) | gi, iv);
            int p2 = atomicAdd(&cnt[gi >> 6], 1);
            tmp[p2] = make_int2(((gi & 63) << 19) | r, iv);
        }
    }
}

// Concat + convert f32 embeddings -> bf16 table [nR][D].
__global__ void convert_e0(const float* __restrict__ Eu,
                           const float* __restrict__ Ei,
                           unsigned short* __restrict__ Ecat,
                           long long nuD, long long nD) {
    long long stride = (long long)gridDim.x * blockDim.x * 4;
    for (long long i = ((long long)blockIdx.x * blockDim.x + threadIdx.x) * 4;
         i < nD; i += stride) {
        const float* src = (i < nuD) ? (Eu + i) : (Ei + (i - nuD));
        float4 f = *(const float4*)src;
        unsigned short o0 = f32_to_bf16(f.x), o1 = f32_to_bf16(f.y);
        unsigned short o2 = f32_to_bf16(f.z), o3 = f32_to_bf16(f.w);
        *(uint2*)(Ecat + i) =
            make_uint2(((unsigned)o1 << 16) | o0, ((unsigned)o3 << 16) | o2);
    }
}

// ---------------- fused sort + layer-1 accumulate ----------------
// Phase 1: stage bucket entries, bin by local row (uint16 index), write
// rowStart + sorted tmp back. Phase 2: 4 gather slots per row pair (stride 8),
// entries from LDS, gathers issued 1 iter ahead.
__global__ __launch_bounds__(512) void accum_sort_l1(
    int2* __restrict__ tmp, const int* __restrict__ bktBase,
    int* __restrict__ rowStart,
    const unsigned short* __restrict__ gsrc,  // bf16 [nR][D] gather source
    unsigned short* __restrict__ Zout,        // bf16 [nR][D] layer-1 output
    int nu, int nR) {
    __shared__ int2 stage[REF_CAP];
    __shared__ unsigned short idx[REF_CAP];
    __shared__ int h[RPB], cur[RPB], rs[RPB + 1];
    int b = blockIdx.x;
    int beg = bktBase[b], end = bktBase[b + 1];
    int n = end - beg;
    int t = threadIdx.x;
    if (t < RPB) h[t] = 0;
    if (t == 0) { stage[0] = make_int2(0, 0); idx[0] = 0; }
    __syncthreads();

    int w = t >> 6, lane = t & 63;
    int q = lane >> 4, m = lane & 15;
    const uint2* gp = (const uint2*)gsrc + m;  // lane's dim slot (row stride 16)

    if (n <= REF_CAP) {
        // ---- phase 1: stage + bin-by-row ----
        for (int e = t; e < n; e += 512) {
            int2 v = tmp[beg + e];
            stage[e] = v;
            atomicAdd(&h[(v.x >> 19) & (RPB - 1)], 1);
        }
        __syncthreads();
        int myc = (t < RPB) ? h[t] : 0;
        for (int off = 1; off < RPB; off <<= 1) {   // Hillis-Steele over 64 bins
            int x = 0;
            if (t < RPB && t >= off) x = h[t - off];
            __syncthreads();
            if (t < RPB) h[t] += x;
            __syncthreads();
        }
        if (t < RPB) {
            int excl = h[t] - myc;                  // bucket-local exclusive
            cur[t] = excl;
            rs[t] = excl;
            rowStart[(size_t)b * RPB + t] = beg + excl;
        }
        if (t == 0) rs[RPB] = n;
        __syncthreads();
        for (int e = t; e < n; e += 512) {
            int2 v = stage[e];
            int p = atomicAdd(&cur[(v.x >> 19) & (RPB - 1)], 1);
            idx[p] = (unsigned short)e;
        }
        __syncthreads();
        // write sorted entries back for layer 2 (coalesced stores)
        for (int e = t; e < n; e += 512) tmp[beg + e] = stage[idx[e]];

        // ---- phase 2: accumulate from LDS entries, 4 gather slots ----
        for (int k = 0; k < 8; k += 2) {
            int rlA = (w << 3) + k;
            int grA = b * RPB + rlA;
            if (grA >= nR) break;
            bool hasB = (grA + 1) < nR;
            int eA0 = rs[rlA], eA1 = rs[rlA + 1];
            int eB0 = eA1;
            int eB1 = hasB ? rs[rlA + 2] : eA1;
            int nA = eA1 - eA0, nB = eB1 - eB0;
            int iters = ((nA > nB ? nA : nB) + 7) >> 3;

            float a0 = 0.f, a1 = 0.f, a2 = 0.f, a3 = 0.f;
            float b0 = 0.f, b1 = 0.f, b2 = 0.f, b3 = 0.f;
            int eA = eA0 + q, eB = eB0 + q;

            bool oA0 = eA < eA1,     oA1 = eA + 4 < eA1;
            bool oB0 = eB < eB1,     oB1 = eB + 4 < eB1;
            int2 sA0 = stage[idx[oA0 ? eA : 0]];
            int2 sA1 = stage[idx[oA1 ? eA + 4 : 0]];
            int2 sB0 = stage[idx[oB0 ? eB : 0]];
            int2 sB1 = stage[idx[oB1 ? eB + 4 : 0]];
            uint2 gA0 = gp[(oA0 ? (sA0.x & 0x7FFFF) : 0) << 4];
            uint2 gA1 = gp[(oA1 ? (sA1.x & 0x7FFFF) : 0) << 4];
            uint2 gB0 = gp[(oB0 ? (sB0.x & 0x7FFFF) : 0) << 4];
            uint2 gB1 = gp[(oB1 ? (sB1.x & 0x7FFFF) : 0) << 4];
            float vA0 = oA0 ? __int_as_float(sA0.y) : 0.f;
            float vA1 = oA1 ? __int_as_float(sA1.y) : 0.f;
            float vB0 = oB0 ? __int_as_float(sB0.y) : 0.f;
            float vB1 = oB1 ? __int_as_float(sB1.y) : 0.f;

            for (int i = 0; i < iters; i++) {
                bool nA0 = eA + 8 < eA1,  nA1 = eA + 12 < eA1;
                bool nB0 = eB + 8 < eB1,  nB1 = eB + 12 < eB1;
                int2 tA0 = stage[idx[nA0 ? eA + 8 : 0]];
                int2 tA1 = stage[idx[nA1 ? eA + 12 : 0]];
                int2 tB0 = stage[idx[nB0 ? eB + 8 : 0]];
                int2 tB1 = stage[idx[nB1 ? eB + 12 : 0]];

                a0 += vA0 * bf16_lo(gA0.x); a1 += vA0 * bf16_hi(gA0.x);
                a2 += vA0 * bf16_lo(gA0.y); a3 += vA0 * bf16_hi(gA0.y);
                a0 += vA1 * bf16_lo(gA1.x); a1 += vA1 * bf16_hi(gA1.x);
                a2 += vA1 * bf16_lo(gA1.y); a3 += vA1 * bf16_hi(gA1.y);
                b0 += vB0 * bf16_lo(gB0.x); b1 += vB0 * bf16_hi(gB0.x);
                b2 += vB0 * bf16_lo(gB0.y); b3 += vB0 * bf16_hi(gB0.y);
                b0 += vB1 * bf16_lo(gB1.x); b1 += vB1 * bf16_hi(gB1.x);
                b2 += vB1 * bf16_lo(gB1.y); b3 += vB1 * bf16_hi(gB1.y);

                gA0 = gp[(nA0 ? (tA0.x & 0x7FFFF) : 0) << 4];
                gA1 = gp[(nA1 ? (tA1.x & 0x7FFFF) : 0) << 4];
                gB0 = gp[(nB0 ? (tB0.x & 0x7FFFF) : 0) << 4];
                gB1 = gp[(nB1 ? (tB1.x & 0x7FFFF) : 0) << 4];
                vA0 = nA0 ? __int_as_float(tA0.y) : 0.f;
                vA1 = nA1 ? __int_as_float(tA1.y) : 0.f;
                vB0 = nB0 ? __int_as_float(tB0.y) : 0.f;
                vB1 = nB1 ? __int_as_float(tB1.y) : 0.f;
                eA += 8; eB += 8;
            }

            a0 += __shfl_xor(a0, 16, 64); a0 += __shfl_xor(a0, 32, 64);
            a1 += __shfl_xor(a1, 16, 64); a1 += __shfl_xor(a1, 32, 64);
            a2 += __shfl_xor(a2, 16, 64); a2 += __shfl_xor(a2, 32, 64);
            a3 += __shfl_xor(a3, 16, 64); a3 += __shfl_xor(a3, 32, 64);
            b0 += __shfl_xor(b0, 16, 64); b0 += __shfl_xor(b0, 32, 64);
            b1 += __shfl_xor(b1, 16, 64); b1 += __shfl_xor(b1, 32, 64);
            b2 += __shfl_xor(b2, 16, 64); b2 += __shfl_xor(b2, 32, 64);
            b3 += __shfl_xor(b3, 16, 64); b3 += __shfl_xor(b3, 32, 64);

            int wr = (q == 0) ? grA : ((q == 1 && hasB) ? grA + 1 : -1);
            if (wr >= 0) {
                float r0 = (q == 0) ? a0 : b0;
                float r1 = (q == 0) ? a1 : b1;
                float r2 = (q == 0) ? a2 : b2;
                float r3 = (q == 0) ? a3 : b3;
                long long o = (long long)wr * D + m * 4;
                unsigned p0 = ((unsigned)f32_to_bf16(r1) << 16) | f32_to_bf16(r0);
                unsigned p1 = ((unsigned)f32_to_bf16(r3) << 16) | f32_to_bf16(r2);
                *(uint2*)(Zout + o) = make_uint2(p0, p1);
            }
        }
    } else {
        // oversized bucket: sentinel + unsorted global scan+filter accumulate
        if (t < RPB) rowStart[(size_t)b * RPB + t] = (t == 0) ? -(beg + 1) : 0;
        __syncthreads();
        for (int k = 0; k < 8; k += 2) {
            int rlA = (w << 3) + k;
            int grA = b * RPB + rlA;
            if (grA >= nR) break;
            bool hasB = (grA + 1) < nR;
            float a0 = 0.f, a1 = 0.f, a2 = 0.f, a3 = 0.f;
            float b0 = 0.f, b1 = 0.f, b2 = 0.f, b3 = 0.f;
            int iters = (n + 3) >> 2;
            int e = beg + q;
            for (int i = 0; i < iters; i++) {
                int2 s = (e < end) ? tmp[e] : make_int2(0, 0);
                int rl = (s.x >> 19) & (RPB - 1);
                bool okA = (e < end) && (rl == rlA);
                bool okB = (e < end) && hasB && (rl == rlA + 1);
                int rx = (okA | okB) ? (s.x & 0x7FFFF) : 0;
                float vA = okA ? __int_as_float(s.y) : 0.f;
                float vB = okB ? __int_as_float(s.y) : 0.f;
                uint2 g = gp[rx << 4];
                a0 += vA * bf16_lo(g.x); a1 += vA * bf16_hi(g.x);
                a2 += vA * bf16_lo(g.y); a3 += vA * bf16_hi(g.y);
                b0 += vB * bf16_lo(g.x); b1 += vB * bf16_hi(g.x);
                b2 += vB * bf16_lo(g.y); b3 += vB * bf16_hi(g.y);
                e += 4;
            }
            a0 += __shfl_xor(a0, 16, 64); a0 += __shfl_xor(a0, 32, 64);
            a1 += __shfl_xor(a1, 16, 64); a1 += __shfl_xor(a1, 32, 64);
            a2 += __shfl_xor(a2, 16, 64); a2 += __shfl_xor(a2, 32, 64);
            a3 += __shfl_xor(a3, 16, 64); a3 += __shfl_xor(a3, 32, 64);
            b0 += __shfl_xor(b0, 16, 64); b0 += __shfl_xor(b0, 32, 64);
            b1 += __shfl_xor(b1, 16, 64); b1 += __shfl_xor(b1, 32, 64);
            b2 += __shfl_xor(b2, 16, 64); b2 += __shfl_xor(b2, 32, 64);
            b3 += __shfl_xor(b3, 16, 64); b3 += __shfl_xor(b3, 32, 64);
            int wr = (q == 0) ? grA : ((q == 1 && hasB) ? grA + 1 : -1);
            if (wr >= 0) {
                float r0 = (q == 0) ? a0 : b0;
                float r1 = (q == 0) ? a1 : b1;
                float r2 = (q == 0) ? a2 : b2;
                float r3 = (q == 0) ? a3 : b3;
                long long o = (long long)wr * D + m * 4;
                unsigned p0 = ((unsigned)f32_to_bf16(r1) << 16) | f32_to_bf16(r0);
                unsigned p1 = ((unsigned)f32_to_bf16(r3) << 16) | f32_to_bf16(r2);
                *(uint2*)(Zout + o) = make_uint2(p0, p1);
            }
        }
    }
}

// ---------------- layer-2 accumulate: 4 gather slots, full occupancy -------
// 256 thr / (256,8): 8 blocks/CU = 32 waves/CU; VGPR cap 64 keeps occupancy.
// Wave w owns rows [8w,8w+8) in pairs (A,B). Quarter q handles entries
// e0+q, e0+q+4 (stride 8). tmp 2 iters ahead; 4 gathers issued 1 iter ahead.
// Fused combine reads Ecat (bf16 E0) -> out = (E0 + Z1 + sum)/3.
__global__ __launch_bounds__(256, 8) void accum8_kernel(
    const int2* __restrict__ tmp, const int* __restrict__ bktBase,
    const int* __restrict__ rowStart,
    const unsigned short* __restrict__ gsrc,  // bf16 [nR][D] gather source (Z1)
    const unsigned short* __restrict__ Ecat,  // bf16 [nR][D] E0 (linear)
    const unsigned short* __restrict__ Z1,    // bf16 [nR][D] Z1 (linear)
    float* __restrict__ out,                  // f32 [nR][D]
    int nu, int nR) {
    int b = blockIdx.x;
    int w = threadIdx.x >> 6, lane = threadIdx.x & 63;
    int q = lane >> 4, m = lane & 15;
    int rb64 = (b * ACC) >> 6;            // enclosing 64-row sort bucket
    int bEnd = bktBase[rb64 + 1];
    int rb0 = rowStart[(size_t)rb64 << 6];
    bool sorted = (rb0 >= 0);
    const uint2* gp = (const uint2*)gsrc + m;  // lane's dim slot (row stride 16)

    for (int k = 0; k < 8; k += 2) {
        int grA = b * ACC + (w << 3) + k;
        if (grA >= nR) break;
        bool hasB = (grA + 1) < nR;

        float a0 = 0.f, a1 = 0.f, a2 = 0.f, a3 = 0.f;
        float b0 = 0.f, b1 = 0.f, b2 = 0.f, b3 = 0.f;

        if (sorted) {
            int eA0 = rowStart[grA], eA1 = rowStart[grA + 1];
            int eB0 = eA1;
            int eB1 = hasB ? (((grA & 63) == 62) ? bEnd : rowStart[grA + 2])
                           : eB0;
            int nA = eA1 - eA0, nB = eB1 - eB0;
            int nMax = nA > nB ? nA : nB;
            int iters = (nMax + 7) >> 3;
            int eA = eA0 + q, eB = eB0 + q;

            // prologue: tmp i=0, gathers i=0, tmp i=1
            int2 cA0 = tmp[eA],      cA1 = tmp[eA + 4];
            int2 cB0 = tmp[eB],      cB1 = tmp[eB + 4];
            bool oA0 = eA < eA1,     oA1 = eA + 4 < eA1;
            bool oB0 = eB < eB1,     oB1 = eB + 4 < eB1;
            uint2 gA0 = gp[(oA0 ? (cA0.x & 0x7FFFF) : 0) << 4];
            uint2 gA1 = gp[(oA1 ? (cA1.x & 0x7FFFF) : 0) << 4];
            uint2 gB0 = gp[(oB0 ? (cB0.x & 0x7FFFF) : 0) << 4];
            uint2 gB1 = gp[(oB1 ? (cB1.x & 0x7FFFF) : 0) << 4];
            float vA0 = oA0 ? __int_as_float(cA0.y) : 0.f;
            float vA1 = oA1 ? __int_as_float(cA1.y) : 0.f;
            float vB0 = oB0 ? __int_as_float(cB0.y) : 0.f;
            float vB1 = oB1 ? __int_as_float(cB1.y) : 0.f;
            int2 sA0 = tmp[eA + 8],  sA1 = tmp[eA + 12];
            int2 sB0 = tmp[eB + 8],  sB1 = tmp[eB + 12];

            for (int i = 0; i < iters; i++) {
                int2 tA0 = tmp[eA + 16], tA1 = tmp[eA + 20];
                int2 tB0 = tmp[eB + 16], tB1 = tmp[eB + 20];

                a0 += vA0 * bf16_lo(gA0.x); a1 += vA0 * bf16_hi(gA0.x);
                a2 += vA0 * bf16_lo(gA0.y); a3 += vA0 * bf16_hi(gA0.y);
                a0 += vA1 * bf16_lo(gA1.x); a1 += vA1 * bf16_hi(gA1.x);
                a2 += vA1 * bf16_lo(gA1.y); a3 += vA1 * bf16_hi(gA1.y);
                b0 += vB0 * bf16_lo(gB0.x); b1 += vB0 * bf16_hi(gB0.x);
                b2 += vB0 * bf16_lo(gB0.y); b3 += vB0 * bf16_hi(gB0.y);
                b0 += vB1 * bf16_lo(gB1.x); b1 += vB1 * bf16_hi(gB1.x);
                b2 += vB1 * bf16_lo(gB1.y); b3 += vB1 * bf16_hi(gB1.y);

                bool nA0 = eA + 8 < eA1,  nA1 = eA + 12 < eA1;
                bool nB0 = eB + 8 < eB1,  nB1 = eB + 12 < eB1;
                gA0 = gp[(nA0 ? (sA0.x & 0x7FFFF) : 0) << 4];
                gA1 = gp[(nA1 ? (sA1.x & 0x7FFFF) : 0) << 4];
                gB0 = gp[(nB0 ? (sB0.x & 0x7FFFF) : 0) << 4];
                gB1 = gp[(nB1 ? (sB1.x & 0x7FFFF) : 0) << 4];
                vA0 = nA0 ? __int_as_float(sA0.y) : 0.f;
                vA1 = nA1 ? __int_as_float(sA1.y) : 0.f;
                vB0 = nB0 ? __int_as_float(sB0.y) : 0.f;
                vB1 = nB1 ? __int_as_float(sB1.y) : 0.f;

                sA0 = tA0; sA1 = tA1; sB0 = tB0; sB1 = tB1;
                eA += 8; eB += 8;
            }
        } else {
            int beg = -(rb0 + 1);
            int n = bEnd - beg;
            int iters = (n + 3) >> 2;
            int e = beg + q;
            int rlA = grA & 63;
            for (int i = 0; i < iters; i++) {
                int2 s = tmp[e];
                int rl = (s.x >> 19) & 63;
                bool in = e < bEnd;
                bool okA = in && (rl == rlA);
                bool okB = in && hasB && (rl == rlA + 1);
                int rx = (okA | okB) ? (s.x & 0x7FFFF) : 0;
                float vA = okA ? __int_as_float(s.y) : 0.f;
                float vB = okB ? __int_as_float(s.y) : 0.f;
                uint2 g = gp[rx << 4];
                a0 += vA * bf16_lo(g.x); a1 += vA * bf16_hi(g.x);
                a2 += vA * bf16_lo(g.y); a3 += vA * bf16_hi(g.y);
                b0 += vB * bf16_lo(g.x); b1 += vB * bf16_hi(g.x);
                b2 += vB * bf16_lo(g.y); b3 += vB * bf16_hi(g.y);
                e += 4;
            }
        }

        a0 += __shfl_xor(a0, 16, 64); a0 += __shfl_xor(a0, 32, 64);
        a1 += __shfl_xor(a1, 16, 64); a1 += __shfl_xor(a1, 32, 64);
        a2 += __shfl_xor(a2, 16, 64); a2 += __shfl_xor(a2, 32, 64);
        a3 += __shfl_xor(a3, 16, 64); a3 += __shfl_xor(a3, 32, 64);
        b0 += __shfl_xor(b0, 16, 64); b0 += __shfl_xor(b0, 32, 64);
        b1 += __shfl_xor(b1, 16, 64); b1 += __shfl_xor(b1, 32, 64);
        b2 += __shfl_xor(b2, 16, 64); b2 += __shfl_xor(b2, 32, 64);
        b3 += __shfl_xor(b3, 16, 64); b3 += __shfl_xor(b3, 32, 64);

        int wr = (q == 0) ? grA : ((q == 1 && hasB) ? grA + 1 : -1);
        if (wr >= 0) {
            float r0 = (q == 0) ? a0 : b0;
            float r1 = (q == 0) ? a1 : b1;
            float r2 = (q == 0) ? a2 : b2;
            float r3 = (q == 0) ? a3 : b3;
            long long o = (long long)wr * D + m * 4;
            uint2 ez = *(const uint2*)(Ecat + o);
            uint2 z  = *(const uint2*)(Z1 + o);
            const float inv3 = 1.f / 3.f;
            float4 ov;
            ov.x = (bf16_lo(ez.x) + bf16_lo(z.x) + r0) * inv3;
            ov.y = (bf16_hi(ez.x) + bf16_hi(z.x) + r1) * inv3;
            ov.z = (bf16_lo(ez.y) + bf16_lo(z.y) + r2) * inv3;
            ov.w = (bf16_hi(ez.y) + bf16_hi(z.y) + r3) * inv3;
            *(float4*)(out + o) = ov;
        }
    }
}

// ---------------- fallback (atomic scatter, needs only 77 MB ws) ----------------

__global__ void spmm_edge(const float* __restrict__ vals,
                          const int* __restrict__ rows,
                          const int* __restrict__ cols,
                          const float* __restrict__ Eu,
                          const float* __restrict__ Ei,
                          float* __restrict__ Zu, float* __restrict__ Zi,
                          float scale, int nnz) {
    long long gid = (long long)blockIdx.x * blockDim.x + threadIdx.x;
    if (gid >= (long long)nnz * D) return;
    int e = (int)(gid >> 6);
    int d = (int)(gid & 63);
    float v = vals[e] * scale;
    long long r = rows[e];
    long long c = cols[e];
    atomicAdd(&Zu[r * D + d], v * Ei[c * D + d]);
    atomicAdd(&Zi[c * D + d], v * Eu[r * D + d]);
}

__global__ void combine_kernel(const float* __restrict__ E0,
                               const float* __restrict__ Z1,
                               float* __restrict__ out, long long n4) {
    long long i = (long long)blockIdx.x * blockDim.x + threadIdx.x;
    if (i >= n4) return;
    const float4 a = reinterpret_cast<const float4*>(E0)[i];
    const float4 b = reinterpret_cast<const float4*>(Z1)[i];
    const float inv3 = 1.0f / 3.0f;
    float4 o;
    o.x = (a.x + b.x) * inv3;
    o.y = (a.y + b.y) * inv3;
    o.z = (a.z + b.z) * inv3;
    o.w = (a.w + b.w) * inv3;
    reinterpret_cast<float4*>(out)[i] = o;
}

// ---------------- launcher ----------------

static inline size_t align256(size_t x) { return (x + 255) & ~(size_t)255; }

extern "C" void kernel_launch(void* const* d_in, const int* in_sizes, int n_in,
                              void* d_out, int out_size, void* d_ws, size_t ws_size,
                              hipStream_t stream) {
    const float* user_emb = (const float*)d_in[0];
    const float* item_emb = (const float*)d_in[1];
    const float* vals     = (const float*)d_in[2];
    const int*   rows     = (const int*)d_in[3];
    const int*   cols     = (const int*)d_in[4];

    const int nu  = in_sizes[0] / D;  // 100000
    const int ni  = in_sizes[1] / D;  // 200000
    const int nnz = in_sizes[2];      // 5000000
    const int nR  = nu + ni;
    const int NB  = (nR + RPB - 1) / RPB;              // 4688
    const int NBLK = (nnz + PASSB_EDGES - 1) / PASSB_EDGES;  // 611

    float* out = (float*)d_out;  // [nR][D], users then items

    // common ws layout (tmp has +32 slack for pipelined overshoot reads)
    size_t off = 0;
    size_t o_tmp  = off; off += align256(((size_t)2 * nnz + 32) * sizeof(int2));
    size_t o_E    = off; off += align256((size_t)nR * D * sizeof(unsigned short));
    size_t o_Z1   = off; off += align256((size_t)nR * D * sizeof(unsigned short));
    size_t o_cnt  = off; off += align256((size_t)(NB + 1) * sizeof(int));
    size_t o_base = off; off += align256((size_t)(NB + 2) * sizeof(int));
    size_t o_cur  = off; off += align256((size_t)(NB + 1) * sizeof(int));
    size_t o_row  = off; off += align256(((size_t)NB * RPB + 1) * sizeof(int));
    size_t needed_mid = off;
    // extra for deterministic build
    size_t o_c16  = off; off += align256((size_t)NB * NBLK * sizeof(unsigned short));
    size_t o_offs = off; off += align256((size_t)NB * NBLK * sizeof(int));
    size_t needed_new = off;

    bool fits19 = (nR < (1 << 19));  // src index must pack in 19 bits

    if (ws_size >= needed_mid && NB <= NBMAX && fits19) {
        char* w = (char*)d_ws;
        int2*           tmp      = (int2*)(w + o_tmp);
        unsigned short* Ecat     = (unsigned short*)(w + o_E);
        unsigned short* Z1bf     = (unsigned short*)(w + o_Z1);
        int*            bktCnt   = (int*)(w + o_cnt);
        int*            bktBase  = (int*)(w + o_base);
        int*            bktCur   = (int*)(w + o_cur);
        int*            rowStart = (int*)(w + o_row);

        if (ws_size >= needed_new) {
            // deterministic bucket build: zero global atomics
            unsigned short* cnts16 = (unsigned short*)(w + o_c16);
            int*            offs   = (int*)(w + o_offs);

            count_kernel<<<NBLK, 1024, 0, stream>>>(rows, cols, cnts16,
                                                    nu, nnz, NB);
            scanA_kernel<<<NB, 64, 0, stream>>>(cnts16, offs, bktCnt, NB, NBLK);
            scan_buckets<<<1, 256, 0, stream>>>(bktCnt, bktBase, bktCur,
                                                NB, 2 * nnz);
            passB_kernel<<<NBLK, 1024, 0, stream>>>(vals, rows, cols, bktBase,
                                                    offs, tmp, nu, nnz, NB, NBLK);
        } else {
            // mid-tier: global-atomic chunk reservation
            hipMemsetAsync(bktCnt, 0, (size_t)NB * sizeof(int), stream);
            bucket_hist<<<512, 1024, 0, stream>>>(rows, cols, bktCnt,
                                                  nu, nnz, NB);
            scan_buckets<<<1, 256, 0, stream>>>(bktCnt, bktBase, bktCur,
                                                NB, 2 * nnz);
            pass_bucket<<<NBLK, 1024, 0, stream>>>(vals, rows, cols, bktCur,
                                                   tmp, nu, nnz, NB);
        }

        long long nD = (long long)nR * D;
        long long nuD = (long long)nu * D;
        unsigned gC = (unsigned)((nD / 4 + 255) / 256);
        if (gC > 4096) gC = 4096;
        convert_e0<<<gC, 256, 0, stream>>>(user_emb, item_emb, Ecat, nuD, nD);

        // Fused: sort buckets by row (write rowStart + sorted tmp) and
        // compute layer 1: Z1 = A_cat @ E0
        accum_sort_l1<<<NB, 512, 0, stream>>>(tmp, bktBase, rowStart, Ecat,
                                              Z1bf, nu, nR);

        // Layer 2 + combine: out = (E0 + Z1 + A_cat @ Z1) / 3
        unsigned gA = (unsigned)((nR + ACC - 1) / ACC);  // 9375
        accum8_kernel<<<gA, 256, 0, stream>>>(
            tmp, bktBase, rowStart, Z1bf, Ecat, Z1bf, out, nu, nR);
    } else {
        // Fallback: atomic scatter, needs only (nu+ni)*D*4 bytes of ws.
        float* Zu1 = (float*)d_ws;
        float* Zi1 = Zu1 + (size_t)nu * D;
        float* out_u = out;
        float* out_i = out + (size_t)nu * D;
        hipMemsetAsync(d_ws, 0, (size_t)nR * D * sizeof(float), stream);

        const int threads = 256;
        long long tot = (long long)nnz * D;
        unsigned blocks = (unsigned)((tot + threads - 1) / threads);

        spmm_edge<<<blocks, threads, 0, stream>>>(vals, rows, cols, user_emb,
                                                  item_emb, Zu1, Zi1, 1.0f, nnz);
        long long nu4 = (long long)nu * D / 4;
        long long ni4 = (long long)ni * D / 4;
        combine_kernel<<<(unsigned)((nu4 + 255) / 256), 256, 0, stream>>>(
            user_emb, Zu1, out_u, nu4);
        combine_kernel<<<(unsigned)((ni4 + 255) / 256), 256, 0, stream>>>(
            item_emb, Zi1, out_i, ni4);
        spmm_edge<<<blocks, threads, 0, stream>>>(vals, rows, cols, Zu1, Zi1,
                                                  out_u, out_i, 1.0f / 3.0f, nnz);
    }
}

// Round 14
// 685.213 us; speedup vs baseline: 1.0446x; 1.0446x over previous
//
#include <hip/hip_runtime.h>

// LightGCL forward: 2 layers of bipartite SpMM + mean of layer embeddings.
// Deterministic bucket build (no global atomics): per-block LDS histograms ->
// cnts16, per-bucket scan -> exact chunk offsets, atomic-free emit. Fused
// sort-by-row + layer-1 accumulate per 64-row bucket (LDS staging); layer-2
// accumulate streams sorted entries with the proven 2-slot 2-deep pipeline
// (accum7, 256 thr, launch_bounds(256,8), 242us) and a bf16 fused combine.
// No atomics and no LDS in any gather hot loop.

constexpr int D = 64;
constexpr int RPB = 64;             // rows per sort bucket
constexpr int ACC = 32;             // rows per accum-L2 block
constexpr int NBMAX = 5120;         // LDS histogram capacity
constexpr int REF_CAP = 4000;       // sort LDS staging capacity (entries)
constexpr int PASSB_EDGES = 8192;   // edges per block in count/emit

static __device__ __forceinline__ unsigned short f32_to_bf16(float f) {
    unsigned u = __float_as_uint(f);
    unsigned r = u + 0x7FFFu + ((u >> 16) & 1u);
    return (unsigned short)(r >> 16);
}
static __device__ __forceinline__ float bf16_lo(unsigned g) {
    return __uint_as_float(g << 16);
}
static __device__ __forceinline__ float bf16_hi(unsigned g) {
    return __uint_as_float(g & 0xFFFF0000u);
}

// ---------------- deterministic bucket build (no global atomics) ----------

__global__ __launch_bounds__(1024) void count_kernel(
    const int* __restrict__ rows, const int* __restrict__ cols,
    unsigned short* __restrict__ cnts16, int nu, int nnz, int NB) {
    __shared__ int cnt[NBMAX];
    for (int i = threadIdx.x; i < NB; i += 1024) cnt[i] = 0;
    __syncthreads();
    int base = blockIdx.x * PASSB_EDGES;
    for (int k = 0; k < PASSB_EDGES / 1024; k++) {
        int e = base + k * 1024 + threadIdx.x;
        if (e < nnz) {
            atomicAdd(&cnt[rows[e] >> 6], 1);
            atomicAdd(&cnt[(nu + cols[e]) >> 6], 1);
        }
    }
    __syncthreads();
    for (int i = threadIdx.x; i < NB; i += 1024)
        cnts16[(size_t)blockIdx.x * NB + i] = (unsigned short)cnt[i];
}

__global__ __launch_bounds__(64) void scanA_kernel(
    const unsigned short* __restrict__ cnts16, int* __restrict__ offs,
    int* __restrict__ totals, int NB, int NBLK) {
    int b = blockIdx.x;
    int lane = threadIdx.x;
    int carry = 0;
    for (int c0 = 0; c0 < NBLK; c0 += 64) {
        int blk = c0 + lane;
        int v = (blk < NBLK) ? (int)cnts16[(size_t)blk * NB + b] : 0;
        int x = v;
        for (int off = 1; off < 64; off <<= 1) {
            int n = __shfl_up(x, off, 64);
            if (lane >= off) x += n;
        }
        if (blk < NBLK) offs[(size_t)b * NBLK + blk] = carry + x - v;
        carry += __shfl(x, 63, 64);
    }
    if (lane == 0) totals[b] = carry;
}

__global__ void scan_buckets(const int* __restrict__ bktCnt,
                             int* __restrict__ bktBase, int* __restrict__ bktCur,
                             int NB, int total) {
    __shared__ int tsum[256];
    int t = threadIdx.x;
    const int IT = (NB + 255) / 256;  // <= 20
    int v[20];
    int s = 0;
    for (int k = 0; k < IT; k++) {
        int i = t * IT + k;
        v[k] = (i < NB) ? bktCnt[i] : 0;
        s += v[k];
    }
    tsum[t] = s;
    __syncthreads();
    for (int off = 1; off < 256; off <<= 1) {
        int x = (t >= off) ? tsum[t - off] : 0;
        __syncthreads();
        tsum[t] += x;
        __syncthreads();
    }
    int excl = (t > 0) ? tsum[t - 1] : 0;
    for (int k = 0; k < IT; k++) {
        int i = t * IT + k;
        if (i < NB) { bktBase[i] = excl; bktCur[i] = excl; excl += v[k]; }
    }
    if (t == 255) bktBase[NB] = total;
}

__global__ __launch_bounds__(1024) void passB_kernel(
    const float* __restrict__ vals, const int* __restrict__ rows,
    const int* __restrict__ cols, const int* __restrict__ bktBase,
    const int* __restrict__ offs, int2* __restrict__ tmp,
    int nu, int nnz, int NB, int NBLK) {
    __shared__ int cur[NBMAX];
    for (int i = threadIdx.x; i < NB; i += 1024)
        cur[i] = bktBase[i] + offs[(size_t)i * NBLK + blockIdx.x];
    __syncthreads();
    int base = blockIdx.x * PASSB_EDGES;
    for (int k = 0; k < PASSB_EDGES / 1024; k++) {
        int e = base + k * 1024 + threadIdx.x;
        if (e < nnz) {
            int r = rows[e], c = cols[e];
            int iv = __float_as_int(vals[e]);
            int gi = nu + c;
            int p1 = atomicAdd(&cur[r >> 6], 1);
            tmp[p1] = make_int2(((r & 63) << 19) | gi, iv);
            int p2 = atomicAdd(&cur[gi >> 6], 1);
            tmp[p2] = make_int2(((gi & 63) << 19) | r, iv);
        }
    }
}

// ---------------- mid-tier bucket build (global-atomic chunk reservation) --

__global__ __launch_bounds__(1024) void bucket_hist(
    const int* __restrict__ rows, const int* __restrict__ cols,
    int* __restrict__ bktCnt, int nu, int nnz, int NB) {
    __shared__ int cnt[NBMAX];
    for (int i = threadIdx.x; i < NB; i += blockDim.x) cnt[i] = 0;
    __syncthreads();
    int stride = gridDim.x * blockDim.x;
    for (int e = blockIdx.x * blockDim.x + threadIdx.x; e < nnz; e += stride) {
        atomicAdd(&cnt[rows[e] >> 6], 1);
        atomicAdd(&cnt[(nu + cols[e]) >> 6], 1);
    }
    __syncthreads();
    for (int i = threadIdx.x; i < NB; i += blockDim.x)
        if (cnt[i]) atomicAdd(&bktCnt[i], cnt[i]);
}

__global__ __launch_bounds__(1024) void pass_bucket(
    const float* __restrict__ vals, const int* __restrict__ rows,
    const int* __restrict__ cols, int* __restrict__ bktCur,
    int2* __restrict__ tmp, int nu, int nnz, int NB) {
    __shared__ int cnt[NBMAX];
    for (int i = threadIdx.x; i < NB; i += 1024) cnt[i] = 0;
    __syncthreads();
    int base = blockIdx.x * PASSB_EDGES;
    for (int k = 0; k < PASSB_EDGES / 1024; k++) {
        int e = base + k * 1024 + threadIdx.x;
        if (e < nnz) {
            atomicAdd(&cnt[rows[e] >> 6], 1);
            atomicAdd(&cnt[(nu + cols[e]) >> 6], 1);
        }
    }
    __syncthreads();
    for (int i = threadIdx.x; i < NB; i += 1024) {
        int c = cnt[i];
        if (c) cnt[i] = atomicAdd(&bktCur[i], c);
    }
    __syncthreads();
    for (int k = 0; k < PASSB_EDGES / 1024; k++) {
        int e = base + k * 1024 + threadIdx.x;
        if (e < nnz) {
            int r = rows[e], c = cols[e];
            int iv = __float_as_int(vals[e]);
            int gi = nu + c;
            int p1 = atomicAdd(&cnt[r >> 6], 1);
            tmp[p1] = make_int2(((r & 63) << 19) | gi, iv);
            int p2 = atomicAdd(&cnt[gi >> 6], 1);
            tmp[p2] = make_int2(((gi & 63) << 19) | r, iv);
        }
    }
}

// Concat + convert f32 embeddings -> bf16 table [nR][D].
__global__ void convert_e0(const float* __restrict__ Eu,
                           const float* __restrict__ Ei,
                           unsigned short* __restrict__ Ecat,
                           long long nuD, long long nD) {
    long long stride = (long long)gridDim.x * blockDim.x * 4;
    for (long long i = ((long long)blockIdx.x * blockDim.x + threadIdx.x) * 4;
         i < nD; i += stride) {
        const float* src = (i < nuD) ? (Eu + i) : (Ei + (i - nuD));
        float4 f = *(const float4*)src;
        unsigned short o0 = f32_to_bf16(f.x), o1 = f32_to_bf16(f.y);
        unsigned short o2 = f32_to_bf16(f.z), o3 = f32_to_bf16(f.w);
        *(uint2*)(Ecat + i) =
            make_uint2(((unsigned)o1 << 16) | o0, ((unsigned)o3 << 16) | o2);
    }
}

// ---------------- fused sort + layer-1 accumulate ----------------
__global__ __launch_bounds__(512) void accum_sort_l1(
    int2* __restrict__ tmp, const int* __restrict__ bktBase,
    int* __restrict__ rowStart,
    const unsigned short* __restrict__ gsrc,  // bf16 [nR][D] gather source
    unsigned short* __restrict__ Zout,        // bf16 [nR][D] layer-1 output
    int nu, int nR) {
    __shared__ int2 stage[REF_CAP];
    __shared__ unsigned short idx[REF_CAP];
    __shared__ int h[RPB], cur[RPB], rs[RPB + 1];
    int b = blockIdx.x;
    int beg = bktBase[b], end = bktBase[b + 1];
    int n = end - beg;
    int t = threadIdx.x;
    if (t < RPB) h[t] = 0;
    if (t == 0) { stage[0] = make_int2(0, 0); idx[0] = 0; }
    __syncthreads();

    int w = t >> 6, lane = t & 63;
    int q = lane >> 4, m = lane & 15;
    const uint2* gp = (const uint2*)gsrc + m;  // lane's dim slot (row stride 16)

    if (n <= REF_CAP) {
        // ---- phase 1: stage + bin-by-row ----
        for (int e = t; e < n; e += 512) {
            int2 v = tmp[beg + e];
            stage[e] = v;
            atomicAdd(&h[(v.x >> 19) & (RPB - 1)], 1);
        }
        __syncthreads();
        int myc = (t < RPB) ? h[t] : 0;
        for (int off = 1; off < RPB; off <<= 1) {   // Hillis-Steele over 64 bins
            int x = 0;
            if (t < RPB && t >= off) x = h[t - off];
            __syncthreads();
            if (t < RPB) h[t] += x;
            __syncthreads();
        }
        if (t < RPB) {
            int excl = h[t] - myc;                  // bucket-local exclusive
            cur[t] = excl;
            rs[t] = excl;
            rowStart[(size_t)b * RPB + t] = beg + excl;
        }
        if (t == 0) rs[RPB] = n;
        __syncthreads();
        for (int e = t; e < n; e += 512) {
            int2 v = stage[e];
            int p = atomicAdd(&cur[(v.x >> 19) & (RPB - 1)], 1);
            idx[p] = (unsigned short)e;
        }
        __syncthreads();
        // write sorted entries back for layer 2 (coalesced stores)
        for (int e = t; e < n; e += 512) tmp[beg + e] = stage[idx[e]];

        // ---- phase 2: accumulate from LDS entries ----
        for (int k = 0; k < 8; k += 2) {
            int rlA = (w << 3) + k;
            int grA = b * RPB + rlA;
            if (grA >= nR) break;
            bool hasB = (grA + 1) < nR;
            int eA0 = rs[rlA], eA1 = rs[rlA + 1];
            int eB0 = eA1;
            int eB1 = hasB ? rs[rlA + 2] : eA1;
            int nA = eA1 - eA0, nB = eB1 - eB0;
            int iters = ((nA > nB ? nA : nB) + 3) >> 2;

            float a0 = 0.f, a1 = 0.f, a2 = 0.f, a3 = 0.f;
            float b0 = 0.f, b1 = 0.f, b2 = 0.f, b3 = 0.f;
            int eA = eA0 + q, eB = eB0 + q;

            bool okA = eA < eA1, okB = eB < eB1;
            int2 sA = stage[idx[okA ? eA : 0]];
            int2 sB = stage[idx[okB ? eB : 0]];
            uint2 gA = gp[(okA ? (sA.x & 0x7FFFF) : 0) << 4];
            uint2 gB = gp[(okB ? (sB.x & 0x7FFFF) : 0) << 4];
            float vA = okA ? __int_as_float(sA.y) : 0.f;
            float vB = okB ? __int_as_float(sB.y) : 0.f;

            for (int i = 0; i < iters; i++) {
                bool okA1 = (eA + 4) < eA1, okB1 = (eB + 4) < eB1;
                int2 sAn = stage[idx[okA1 ? eA + 4 : 0]];
                int2 sBn = stage[idx[okB1 ? eB + 4 : 0]];

                a0 += vA * bf16_lo(gA.x); a1 += vA * bf16_hi(gA.x);
                a2 += vA * bf16_lo(gA.y); a3 += vA * bf16_hi(gA.y);
                b0 += vB * bf16_lo(gB.x); b1 += vB * bf16_hi(gB.x);
                b2 += vB * bf16_lo(gB.y); b3 += vB * bf16_hi(gB.y);

                gA = gp[(okA1 ? (sAn.x & 0x7FFFF) : 0) << 4];
                gB = gp[(okB1 ? (sBn.x & 0x7FFFF) : 0) << 4];
                vA = okA1 ? __int_as_float(sAn.y) : 0.f;
                vB = okB1 ? __int_as_float(sBn.y) : 0.f;
                eA += 4; eB += 4;
            }

            a0 += __shfl_xor(a0, 16, 64); a0 += __shfl_xor(a0, 32, 64);
            a1 += __shfl_xor(a1, 16, 64); a1 += __shfl_xor(a1, 32, 64);
            a2 += __shfl_xor(a2, 16, 64); a2 += __shfl_xor(a2, 32, 64);
            a3 += __shfl_xor(a3, 16, 64); a3 += __shfl_xor(a3, 32, 64);
            b0 += __shfl_xor(b0, 16, 64); b0 += __shfl_xor(b0, 32, 64);
            b1 += __shfl_xor(b1, 16, 64); b1 += __shfl_xor(b1, 32, 64);
            b2 += __shfl_xor(b2, 16, 64); b2 += __shfl_xor(b2, 32, 64);
            b3 += __shfl_xor(b3, 16, 64); b3 += __shfl_xor(b3, 32, 64);

            int wr = (q == 0) ? grA : ((q == 1 && hasB) ? grA + 1 : -1);
            if (wr >= 0) {
                float r0 = (q == 0) ? a0 : b0;
                float r1 = (q == 0) ? a1 : b1;
                float r2 = (q == 0) ? a2 : b2;
                float r3 = (q == 0) ? a3 : b3;
                long long o = (long long)wr * D + m * 4;
                unsigned p0 = ((unsigned)f32_to_bf16(r1) << 16) | f32_to_bf16(r0);
                unsigned p1 = ((unsigned)f32_to_bf16(r3) << 16) | f32_to_bf16(r2);
                *(uint2*)(Zout + o) = make_uint2(p0, p1);
            }
        }
    } else {
        // oversized bucket: sentinel + unsorted global scan+filter accumulate
        if (t < RPB) rowStart[(size_t)b * RPB + t] = (t == 0) ? -(beg + 1) : 0;
        __syncthreads();
        for (int k = 0; k < 8; k += 2) {
            int rlA = (w << 3) + k;
            int grA = b * RPB + rlA;
            if (grA >= nR) break;
            bool hasB = (grA + 1) < nR;
            float a0 = 0.f, a1 = 0.f, a2 = 0.f, a3 = 0.f;
            float b0 = 0.f, b1 = 0.f, b2 = 0.f, b3 = 0.f;
            int iters = (n + 3) >> 2;
            int e = beg + q;
            for (int i = 0; i < iters; i++) {
                int2 s = (e < end) ? tmp[e] : make_int2(0, 0);
                int rl = (s.x >> 19) & (RPB - 1);
                bool okA = (e < end) && (rl == rlA);
                bool okB = (e < end) && hasB && (rl == rlA + 1);
                int rx = (okA | okB) ? (s.x & 0x7FFFF) : 0;
                float vA = okA ? __int_as_float(s.y) : 0.f;
                float vB = okB ? __int_as_float(s.y) : 0.f;
                uint2 g = gp[rx << 4];
                a0 += vA * bf16_lo(g.x); a1 += vA * bf16_hi(g.x);
                a2 += vA * bf16_lo(g.y); a3 += vA * bf16_hi(g.y);
                b0 += vB * bf16_lo(g.x); b1 += vB * bf16_hi(g.x);
                b2 += vB * bf16_lo(g.y); b3 += vB * bf16_hi(g.y);
                e += 4;
            }
            a0 += __shfl_xor(a0, 16, 64); a0 += __shfl_xor(a0, 32, 64);
            a1 += __shfl_xor(a1, 16, 64); a1 += __shfl_xor(a1, 32, 64);
            a2 += __shfl_xor(a2, 16, 64); a2 += __shfl_xor(a2, 32, 64);
            a3 += __shfl_xor(a3, 16, 64); a3 += __shfl_xor(a3, 32, 64);
            b0 += __shfl_xor(b0, 16, 64); b0 += __shfl_xor(b0, 32, 64);
            b1 += __shfl_xor(b1, 16, 64); b1 += __shfl_xor(b1, 32, 64);
            b2 += __shfl_xor(b2, 16, 64); b2 += __shfl_xor(b2, 32, 64);
            b3 += __shfl_xor(b3, 16, 64); b3 += __shfl_xor(b3, 32, 64);
            int wr = (q == 0) ? grA : ((q == 1 && hasB) ? grA + 1 : -1);
            if (wr >= 0) {
                float r0 = (q == 0) ? a0 : b0;
                float r1 = (q == 0) ? a1 : b1;
                float r2 = (q == 0) ? a2 : b2;
                float r3 = (q == 0) ? a3 : b3;
                long long o = (long long)wr * D + m * 4;
                unsigned p0 = ((unsigned)f32_to_bf16(r1) << 16) | f32_to_bf16(r0);
                unsigned p1 = ((unsigned)f32_to_bf16(r3) << 16) | f32_to_bf16(r2);
                *(uint2*)(Zout + o) = make_uint2(p0, p1);
            }
        }
    }
}

// ---------------- layer-2 accumulate (proven accum7 inner, bf16 combine) ---
// One block per 32-row tile, 4 waves, launch_bounds(256,8) -> 32 waves/CU.
// Wave w owns rows [8w,8w+8) in pairs (A,B); quarter-wave entry streams,
// 2-deep pipeline (tmp 2 iters ahead, gathers 1 iter ahead).
// out[row] = (E0 + Z1 + sum)/3 with E0, Z1 read as bf16.
__global__ __launch_bounds__(256, 8) void accum7_kernel(
    const int2* __restrict__ tmp, const int* __restrict__ bktBase,
    const int* __restrict__ rowStart,
    const unsigned short* __restrict__ gsrc,  // bf16 [nR][D] gather source (Z1)
    const unsigned short* __restrict__ Ecat,  // bf16 [nR][D] E0 (linear)
    const unsigned short* __restrict__ Z1,    // bf16 [nR][D] Z1 (linear)
    float* __restrict__ out,                  // f32 [nR][D]
    int nu, int nR) {
    int b = blockIdx.x;
    int w = threadIdx.x >> 6, lane = threadIdx.x & 63;
    int q = lane >> 4, m = lane & 15;
    int rb64 = (b * ACC) >> 6;            // enclosing 64-row sort bucket
    int bEnd = bktBase[rb64 + 1];
    int rb0 = rowStart[(size_t)rb64 << 6];
    bool sorted = (rb0 >= 0);
    const uint2* gp = (const uint2*)gsrc + m;  // lane's dim slot (row stride 16)

    for (int k = 0; k < 8; k += 2) {
        int grA = b * ACC + (w << 3) + k;
        if (grA >= nR) break;
        bool hasB = (grA + 1) < nR;

        float a0 = 0.f, a1 = 0.f, a2 = 0.f, a3 = 0.f;
        float b0 = 0.f, b1 = 0.f, b2 = 0.f, b3 = 0.f;

        if (sorted) {
            int eA0 = rowStart[grA], eA1 = rowStart[grA + 1];
            int eB0 = eA1;
            int eB1 = hasB ? (((grA & 63) == 62) ? bEnd : rowStart[grA + 2])
                           : eB0;
            int nA = eA1 - eA0, nB = eB1 - eB0;
            int iters = ((nA > nB ? nA : nB) + 3) >> 2;
            int eA = eA0 + q, eB = eB0 + q;

            int2 sAc = tmp[eA], sBc = tmp[eB];
            int2 sAn = tmp[eA + 4], sBn = tmp[eB + 4];
            bool okA = eA < eA1, okB = eB < eB1;
            uint2 gAc = gp[(okA ? (sAc.x & 0x7FFFF) : 0) << 4];
            uint2 gBc = gp[(okB ? (sBc.x & 0x7FFFF) : 0) << 4];
            float vAc = okA ? __int_as_float(sAc.y) : 0.f;
            float vBc = okB ? __int_as_float(sBc.y) : 0.f;

            for (int i = 0; i < iters; i++) {
                int2 sAn2 = tmp[eA + 8];
                int2 sBn2 = tmp[eB + 8];
                bool okA1 = (eA + 4) < eA1;
                bool okB1 = (eB + 4) < eB1;
                uint2 gAn = gp[(okA1 ? (sAn.x & 0x7FFFF) : 0) << 4];
                uint2 gBn = gp[(okB1 ? (sBn.x & 0x7FFFF) : 0) << 4];
                float vAn = okA1 ? __int_as_float(sAn.y) : 0.f;
                float vBn = okB1 ? __int_as_float(sBn.y) : 0.f;

                a0 += vAc * bf16_lo(gAc.x); a1 += vAc * bf16_hi(gAc.x);
                a2 += vAc * bf16_lo(gAc.y); a3 += vAc * bf16_hi(gAc.y);
                b0 += vBc * bf16_lo(gBc.x); b1 += vBc * bf16_hi(gBc.x);
                b2 += vBc * bf16_lo(gBc.y); b3 += vBc * bf16_hi(gBc.y);

                sAn = sAn2; sBn = sBn2;
                gAc = gAn;  gBc = gBn;
                vAc = vAn;  vBc = vBn;
                eA += 4; eB += 4;
            }
        } else {
            int beg = -(rb0 + 1);
            int n = bEnd - beg;
            int iters = (n + 3) >> 2;
            int e = beg + q;
            int rlA = grA & 63;
            for (int i = 0; i < iters; i++) {
                int2 s = tmp[e];
                int rl = (s.x >> 19) & 63;
                bool in = e < bEnd;
                bool okA = in && (rl == rlA);
                bool okB = in && hasB && (rl == rlA + 1);
                int rx = (okA | okB) ? (s.x & 0x7FFFF) : 0;
                float vA = okA ? __int_as_float(s.y) : 0.f;
                float vB = okB ? __int_as_float(s.y) : 0.f;
                uint2 g = gp[rx << 4];
                a0 += vA * bf16_lo(g.x); a1 += vA * bf16_hi(g.x);
                a2 += vA * bf16_lo(g.y); a3 += vA * bf16_hi(g.y);
                b0 += vB * bf16_lo(g.x); b1 += vB * bf16_hi(g.x);
                b2 += vB * bf16_lo(g.y); b3 += vB * bf16_hi(g.y);
                e += 4;
            }
        }

        a0 += __shfl_xor(a0, 16, 64); a0 += __shfl_xor(a0, 32, 64);
        a1 += __shfl_xor(a1, 16, 64); a1 += __shfl_xor(a1, 32, 64);
        a2 += __shfl_xor(a2, 16, 64); a2 += __shfl_xor(a2, 32, 64);
        a3 += __shfl_xor(a3, 16, 64); a3 += __shfl_xor(a3, 32, 64);
        b0 += __shfl_xor(b0, 16, 64); b0 += __shfl_xor(b0, 32, 64);
        b1 += __shfl_xor(b1, 16, 64); b1 += __shfl_xor(b1, 32, 64);
        b2 += __shfl_xor(b2, 16, 64); b2 += __shfl_xor(b2, 32, 64);
        b3 += __shfl_xor(b3, 16, 64); b3 += __shfl_xor(b3, 32, 64);

        int wr = (q == 0) ? grA : ((q == 1 && hasB) ? grA + 1 : -1);
        if (wr >= 0) {
            float r0 = (q == 0) ? a0 : b0;
            float r1 = (q == 0) ? a1 : b1;
            float r2 = (q == 0) ? a2 : b2;
            float r3 = (q == 0) ? a3 : b3;
            long long o = (long long)wr * D + m * 4;
            uint2 ez = *(const uint2*)(Ecat + o);
            uint2 z  = *(const uint2*)(Z1 + o);
            const float inv3 = 1.f / 3.f;
            float4 ov;
            ov.x = (bf16_lo(ez.x) + bf16_lo(z.x) + r0) * inv3;
            ov.y = (bf16_hi(ez.x) + bf16_hi(z.x) + r1) * inv3;
            ov.z = (bf16_lo(ez.y) + bf16_lo(z.y) + r2) * inv3;
            ov.w = (bf16_hi(ez.y) + bf16_hi(z.y) + r3) * inv3;
            *(float4*)(out + o) = ov;
        }
    }
}

// ---------------- fallback (atomic scatter, needs only 77 MB ws) ----------------

__global__ void spmm_edge(const float* __restrict__ vals,
                          const int* __restrict__ rows,
                          const int* __restrict__ cols,
                          const float* __restrict__ Eu,
                          const float* __restrict__ Ei,
                          float* __restrict__ Zu, float* __restrict__ Zi,
                          float scale, int nnz) {
    long long gid = (long long)blockIdx.x * blockDim.x + threadIdx.x;
    if (gid >= (long long)nnz * D) return;
    int e = (int)(gid >> 6);
    int d = (int)(gid & 63);
    float v = vals[e] * scale;
    long long r = rows[e];
    long long c = cols[e];
    atomicAdd(&Zu[r * D + d], v * Ei[c * D + d]);
    atomicAdd(&Zi[c * D + d], v * Eu[r * D + d]);
}

__global__ void combine_kernel(const float* __restrict__ E0,
                               const float* __restrict__ Z1,
                               float* __restrict__ out, long long n4) {
    long long i = (long long)blockIdx.x * blockDim.x + threadIdx.x;
    if (i >= n4) return;
    const float4 a = reinterpret_cast<const float4*>(E0)[i];
    const float4 b = reinterpret_cast<const float4*>(Z1)[i];
    const float inv3 = 1.0f / 3.0f;
    float4 o;
    o.x = (a.x + b.x) * inv3;
    o.y = (a.y + b.y) * inv3;
    o.z = (a.z + b.z) * inv3;
    o.w = (a.w + b.w) * inv3;
    reinterpret_cast<float4*>(out)[i] = o;
}

// ---------------- launcher ----------------

static inline size_t align256(size_t x) { return (x + 255) & ~(size_t)255; }

extern "C" void kernel_launch(void* const* d_in, const int* in_sizes, int n_in,
                              void* d_out, int out_size, void* d_ws, size_t ws_size,
                              hipStream_t stream) {
    const float* user_emb = (const float*)d_in[0];
    const float* item_emb = (const float*)d_in[1];
    const float* vals     = (const float*)d_in[2];
    const int*   rows     = (const int*)d_in[3];
    const int*   cols     = (const int*)d_in[4];

    const int nu  = in_sizes[0] / D;  // 100000
    const int ni  = in_sizes[1] / D;  // 200000
    const int nnz = in_sizes[2];      // 5000000
    const int nR  = nu + ni;
    const int NB  = (nR + RPB - 1) / RPB;              // 4688
    const int NBLK = (nnz + PASSB_EDGES - 1) / PASSB_EDGES;  // 611

    float* out = (float*)d_out;  // [nR][D], users then items

    // common ws layout (tmp has +32 slack for pipelined overshoot reads)
    size_t off = 0;
    size_t o_tmp  = off; off += align256(((size_t)2 * nnz + 32) * sizeof(int2));
    size_t o_E    = off; off += align256((size_t)nR * D * sizeof(unsigned short));
    size_t o_Z1   = off; off += align256((size_t)nR * D * sizeof(unsigned short));
    size_t o_cnt  = off; off += align256((size_t)(NB + 1) * sizeof(int));
    size_t o_base = off; off += align256((size_t)(NB + 2) * sizeof(int));
    size_t o_cur  = off; off += align256((size_t)(NB + 1) * sizeof(int));
    size_t o_row  = off; off += align256(((size_t)NB * RPB + 1) * sizeof(int));
    size_t needed_mid = off;
    // extra for deterministic build
    size_t o_c16  = off; off += align256((size_t)NB * NBLK * sizeof(unsigned short));
    size_t o_offs = off; off += align256((size_t)NB * NBLK * sizeof(int));
    size_t needed_new = off;

    bool fits19 = (nR < (1 << 19));  // src index must pack in 19 bits

    if (ws_size >= needed_mid && NB <= NBMAX && fits19) {
        char* w = (char*)d_ws;
        int2*           tmp      = (int2*)(w + o_tmp);
        unsigned short* Ecat     = (unsigned short*)(w + o_E);
        unsigned short* Z1bf     = (unsigned short*)(w + o_Z1);
        int*            bktCnt   = (int*)(w + o_cnt);
        int*            bktBase  = (int*)(w + o_base);
        int*            bktCur   = (int*)(w + o_cur);
        int*            rowStart = (int*)(w + o_row);

        if (ws_size >= needed_new) {
            // deterministic bucket build: zero global atomics
            unsigned short* cnts16 = (unsigned short*)(w + o_c16);
            int*            offs   = (int*)(w + o_offs);

            count_kernel<<<NBLK, 1024, 0, stream>>>(rows, cols, cnts16,
                                                    nu, nnz, NB);
            scanA_kernel<<<NB, 64, 0, stream>>>(cnts16, offs, bktCnt, NB, NBLK);
            scan_buckets<<<1, 256, 0, stream>>>(bktCnt, bktBase, bktCur,
                                                NB, 2 * nnz);
            passB_kernel<<<NBLK, 1024, 0, stream>>>(vals, rows, cols, bktBase,
                                                    offs, tmp, nu, nnz, NB, NBLK);
        } else {
            // mid-tier: global-atomic chunk reservation
            hipMemsetAsync(bktCnt, 0, (size_t)NB * sizeof(int), stream);
            bucket_hist<<<512, 1024, 0, stream>>>(rows, cols, bktCnt,
                                                  nu, nnz, NB);
            scan_buckets<<<1, 256, 0, stream>>>(bktCnt, bktBase, bktCur,
                                                NB, 2 * nnz);
            pass_bucket<<<NBLK, 1024, 0, stream>>>(vals, rows, cols, bktCur,
                                                   tmp, nu, nnz, NB);
        }

        long long nD = (long long)nR * D;
        long long nuD = (long long)nu * D;
        unsigned gC = (unsigned)((nD / 4 + 255) / 256);
        if (gC > 4096) gC = 4096;
        convert_e0<<<gC, 256, 0, stream>>>(user_emb, item_emb, Ecat, nuD, nD);

        // Fused: sort buckets by row (write rowStart + sorted tmp) and
        // compute layer 1: Z1 = A_cat @ E0
        accum_sort_l1<<<NB, 512, 0, stream>>>(tmp, bktBase, rowStart, Ecat,
                                              Z1bf, nu, nR);

        // Layer 2 + combine: out = (E0 + Z1 + A_cat @ Z1) / 3
        unsigned gA = (unsigned)((nR + ACC - 1) / ACC);  // 9375
        accum7_kernel<<<gA, 256, 0, stream>>>(
            tmp, bktBase, rowStart, Z1bf, Ecat, Z1bf, out, nu, nR);
    } else {
        // Fallback: atomic scatter, needs only (nu+ni)*D*4 bytes of ws.
        float* Zu1 = (float*)d_ws;
        float* Zi1 = Zu1 + (size_t)nu * D;
        float* out_u = out;
        float* out_i = out + (size_t)nu * D;
        hipMemsetAsync(d_ws, 0, (size_t)nR * D * sizeof(float), stream);

        const int threads = 256;
        long long tot = (long long)nnz * D;
        unsigned blocks = (unsigned)((tot + threads - 1) / threads);

        spmm_edge<<<blocks, threads, 0, stream>>>(vals, rows, cols, user_emb,
                                                  item_emb, Zu1, Zi1, 1.0f, nnz);
        long long nu4 = (long long)nu * D / 4;
        long long ni4 = (long long)ni * D / 4;
        combine_kernel<<<(unsigned)((nu4 + 255) / 256), 256, 0, stream>>>(
            user_emb, Zu1, out_u, nu4);
        combine_kernel<<<(unsigned)((ni4 + 255) / 256), 256, 0, stream>>>(
            item_emb, Zi1, out_i, ni4);
        spmm_edge<<<blocks, threads, 0, stream>>>(vals, rows, cols, Zu1, Zi1,
                                                  out_u, out_i, 1.0f / 3.0f, nnz);
    }
}